// Round 2
// baseline (14824.773 us; speedup 1.0000x reference)
//
#include <hip/hip_runtime.h>
#include <cstddef>

// Problem constants (fixed by the reference).
#define B_   16
#define N_   1024
#define E_   768
#define H_   8
#define D_   96          // E_/H_
#define HID_ 1536        // 2*E_
#define ROWS (B_ * N_)   // 16384
#define SCALE_ 0.03608439182435161f  // 1/sqrt(768)

// ---------------------------------------------------------------------------
// Per-row LayerNorm statistics: mean[row], rstd[row]. One block per row.
// (LN itself is fused into the consuming GEMM's A-tile staging -> no A-sized
//  intermediate buffer.)
// ---------------------------------------------------------------------------
__global__ __launch_bounds__(256) void ln_stats_kernel(const float* __restrict__ x,
                                                       float* __restrict__ mean,
                                                       float* __restrict__ rstd) {
    int row = blockIdx.x;
    int tid = threadIdx.x;
    const float* xr = x + (size_t)row * E_;
    float v0 = xr[tid];
    float v1 = xr[tid + 256];
    float v2 = xr[tid + 512];
    float s  = v0 + v1 + v2;
    float s2 = v0 * v0 + v1 * v1 + v2 * v2;
#pragma unroll
    for (int off = 32; off > 0; off >>= 1) {
        s  += __shfl_down(s, off);
        s2 += __shfl_down(s2, off);
    }
    __shared__ float sb[8];
    int lane = tid & 63, wid = tid >> 6;
    if (lane == 0) { sb[wid] = s; sb[4 + wid] = s2; }
    __syncthreads();
    if (tid == 0) {
        float S  = sb[0] + sb[1] + sb[2] + sb[3];
        float S2 = sb[4] + sb[5] + sb[6] + sb[7];
        float m = S * (1.0f / E_);
        float v = S2 * (1.0f / E_) - m * m;
        mean[row] = m;
        rstd[row] = rsqrtf(v + 1e-5f);
    }
}

// ---------------------------------------------------------------------------
// FP32 tiled GEMM: C[M,N] = act(LN?(A)[M,K] @ W[K,N] + bias) (+ residual)
// BM=BN=64, BK=16, 256 threads, 4x4 microtile per thread.
// Optional fused LN on A (mean/rstd per row, g/beta per k).
// Optional split-store epilogue: n -> (h,d,t) de-interleave into q/k/v[B,H,N,D].
// Assumes M%64==0, N%64==0, K%16==0 (true for all shapes here).
// ---------------------------------------------------------------------------
#define BM 64
#define BN 64
#define BK 16

__device__ __forceinline__ float gelu_exact(float x) {
    return 0.5f * x * (1.0f + erff(x * 0.7071067811865475f));
}

__global__ __launch_bounds__(256) void gemm_kernel(
    const float* __restrict__ A, const float* __restrict__ W,
    const float* __restrict__ bias, const float* __restrict__ residual,
    float* __restrict__ C,
    float* __restrict__ qout, float* __restrict__ kout, float* __restrict__ vout,
    const float* __restrict__ ln_mean, const float* __restrict__ ln_rstd,
    const float* __restrict__ ln_g, const float* __restrict__ ln_beta,
    int M, int N, int K, int do_gelu)
{
    __shared__ float As[BK][BM + 1];  // +1 pad: breaks bank conflicts
    __shared__ float Bs[BK][BN];      // unpadded: keeps float4 stores aligned
    int tid = threadIdx.x;
    int bm = blockIdx.y * BM;
    int bn = blockIdx.x * BN;
    int tx = tid & 15, ty = tid >> 4;
    // A-tile load mapping: 64 rows x 16 k, 4 consecutive k per thread (float4)
    int a_m = tid >> 2;
    int a_k = (tid & 3) << 2;
    // B-tile load mapping: 16 k x 64 n, 4 consecutive n per thread (float4)
    int b_k = tid >> 4;
    int b_n = (tid & 15) << 2;
    const float* Aptr = A + (size_t)(bm + a_m) * K + a_k;
    const float* Wptr = W + (size_t)b_k * N + bn + b_n;

    float lmean = 0.f, lrstd = 1.f;
    if (ln_mean) { lmean = ln_mean[bm + a_m]; lrstd = ln_rstd[bm + a_m]; }

    float acc[4][4] = {};
    for (int k0 = 0; k0 < K; k0 += BK) {
        float4 av = *(const float4*)(Aptr + k0);
        if (ln_mean) {
            float4 gv = *(const float4*)(ln_g + k0 + a_k);
            float4 bv = *(const float4*)(ln_beta + k0 + a_k);
            av.x = (av.x - lmean) * lrstd * gv.x + bv.x;
            av.y = (av.y - lmean) * lrstd * gv.y + bv.y;
            av.z = (av.z - lmean) * lrstd * gv.z + bv.z;
            av.w = (av.w - lmean) * lrstd * gv.w + bv.w;
        }
        float4 wv = *(const float4*)(Wptr + (size_t)k0 * N);
        __syncthreads();
        As[a_k + 0][a_m] = av.x;
        As[a_k + 1][a_m] = av.y;
        As[a_k + 2][a_m] = av.z;
        As[a_k + 3][a_m] = av.w;
        *(float4*)&Bs[b_k][b_n] = wv;
        __syncthreads();
#pragma unroll
        for (int kk = 0; kk < BK; ++kk) {
            float a0 = As[kk][ty * 4 + 0];
            float a1 = As[kk][ty * 4 + 1];
            float a2 = As[kk][ty * 4 + 2];
            float a3 = As[kk][ty * 4 + 3];
            float b0 = Bs[kk][tx * 4 + 0];
            float b1 = Bs[kk][tx * 4 + 1];
            float b2 = Bs[kk][tx * 4 + 2];
            float b3 = Bs[kk][tx * 4 + 3];
            acc[0][0] += a0 * b0; acc[0][1] += a0 * b1; acc[0][2] += a0 * b2; acc[0][3] += a0 * b3;
            acc[1][0] += a1 * b0; acc[1][1] += a1 * b1; acc[1][2] += a1 * b2; acc[1][3] += a1 * b3;
            acc[2][0] += a2 * b0; acc[2][1] += a2 * b1; acc[2][2] += a2 * b2; acc[2][3] += a2 * b3;
            acc[3][0] += a3 * b0; acc[3][1] += a3 * b1; acc[3][2] += a3 * b2; acc[3][3] += a3 * b3;
        }
    }
#pragma unroll
    for (int i = 0; i < 4; ++i) {
        int m = bm + ty * 4 + i;
#pragma unroll
        for (int j = 0; j < 4; ++j) {
            int n = bn + tx * 4 + j;
            float c = acc[i][j] + bias[n];
            if (qout) {
                // de-interleave (h d t): n = (h*D + d)*3 + t  -> q/k/v[B,H,N,D]
                int e = n / 3, t = n - e * 3;
                int hh = e / D_, dd = e - hh * D_;
                int b = m >> 10, ntok = m & (N_ - 1);
                size_t o = (((size_t)b * H_ + hh) * N_ + ntok) * D_ + dd;
                (t == 0 ? qout : t == 1 ? kout : vout)[o] = c;
            } else {
                if (do_gelu) c = gelu_exact(c);
                if (residual) c += residual[(size_t)m * N + n];
                C[(size_t)m * N + n] = c;
            }
        }
    }
}

// ---------------------------------------------------------------------------
// Attention: one block per (b,h,query-row). 256 threads.
// scores (1024) -> softmax -> PV (96 lanes). Writes [b,n,(h d)] layout.
// ---------------------------------------------------------------------------
__global__ __launch_bounds__(256) void attn_kernel(
    const float* __restrict__ q, const float* __restrict__ k,
    const float* __restrict__ v, float* __restrict__ out) {
    int qi = blockIdx.x;
    int bh = blockIdx.y;           // b*H + h
    int b = bh >> 3;               // / H_
    int h = bh & (H_ - 1);
    int tid = threadIdx.x;
    __shared__ float qs[D_];
    __shared__ float sc[N_];
    __shared__ float red[4];
    __shared__ float bc[2];

    const float* qrow = q + ((size_t)bh * N_ + qi) * D_;
    if (tid < D_) qs[tid] = qrow[tid];
    __syncthreads();

    // scores for 4 keys per thread
    float mymax = -1e30f;
#pragma unroll
    for (int s = 0; s < 4; ++s) {
        int m = tid + s * 256;
        const float* krow = k + ((size_t)bh * N_ + m) * D_;
        float acc = 0.f;
#pragma unroll
        for (int i = 0; i < D_ / 4; ++i) {
            float4 kv4 = *(const float4*)(krow + i * 4);
            float4 qv4 = *(const float4*)(qs + i * 4);
            acc += kv4.x * qv4.x + kv4.y * qv4.y + kv4.z * qv4.z + kv4.w * qv4.w;
        }
        acc *= SCALE_;
        sc[m] = acc;
        mymax = fmaxf(mymax, acc);
    }
    int lane = tid & 63, wid = tid >> 6;
#pragma unroll
    for (int off = 32; off > 0; off >>= 1) mymax = fmaxf(mymax, __shfl_down(mymax, off));
    if (lane == 0) red[wid] = mymax;
    __syncthreads();
    if (tid == 0) bc[0] = fmaxf(fmaxf(red[0], red[1]), fmaxf(red[2], red[3]));
    __syncthreads();
    float mx = bc[0];

    float mysum = 0.f;
#pragma unroll
    for (int s = 0; s < 4; ++s) {
        int m = tid + s * 256;
        float e = __expf(sc[m] - mx);
        sc[m] = e;
        mysum += e;
    }
#pragma unroll
    for (int off = 32; off > 0; off >>= 1) mysum += __shfl_down(mysum, off);
    __syncthreads();               // red reuse (tid0 finished reading maxes)
    if (lane == 0) red[wid] = mysum;
    __syncthreads();
    if (tid == 0) bc[1] = red[0] + red[1] + red[2] + red[3];
    __syncthreads();
    float inv = 1.0f / bc[1];

    if (tid < D_) {
        float acc = 0.f;
        const float* vbase = v + (size_t)bh * N_ * D_ + tid;
        for (int m = 0; m < N_; ++m) {
            acc += sc[m] * vbase[(size_t)m * D_];
        }
        out[((size_t)(b * N_ + qi)) * E_ + h * D_ + tid] = acc * inv;
    }
}

// ---------------------------------------------------------------------------
// Orchestration. Workspace (A = B*N*E = 12,582,912 floats) — 3A + 64KB total:
//   phase 1 (attention): q [0,A)  k [A,2A)  v [2A,3A)   (QKV GEMM split-store)
//   phase 2 (FFN):       x1 [0,A)  ffh [A,3A)           (q/k/v dead)
//   stats at [3A): mean1,rstd1,mean2,rstd2 (ROWS each)
//   d_out doubles as the attention-output scratch (dead until final write).
// Peak ws = 3A floats + 256 KB ~= 151.3 MB (was 352 MB -> suspected OOB crash).
// ---------------------------------------------------------------------------
extern "C" void kernel_launch(void* const* d_in, const int* in_sizes, int n_in,
                              void* d_out, int out_size, void* d_ws, size_t ws_size,
                              hipStream_t stream) {
    const float* x      = (const float*)d_in[0];
    const float* ln1_g  = (const float*)d_in[1];
    const float* ln1_b  = (const float*)d_in[2];
    const float* qkv_w  = (const float*)d_in[3];
    const float* qkv_b  = (const float*)d_in[4];
    const float* proj_w = (const float*)d_in[5];
    const float* proj_b = (const float*)d_in[6];
    const float* ln2_g  = (const float*)d_in[7];
    const float* ln2_b  = (const float*)d_in[8];
    const float* ff1_w  = (const float*)d_in[9];
    const float* ff1_b  = (const float*)d_in[10];
    const float* ff2_w  = (const float*)d_in[11];
    const float* ff2_b  = (const float*)d_in[12];
    float* out = (float*)d_out;
    float* ws  = (float*)d_ws;

    const size_t A = (size_t)ROWS * E_;
    float* qb    = ws;            // [0,A)
    float* kb    = ws + A;        // [A,2A)
    float* vb    = ws + 2 * A;    // [2A,3A)
    float* x1    = ws;            // [0,A)   after attention (q dead)
    float* ffh   = ws + A;        // [A,3A)  after attention (k,v dead)
    float* mean1 = ws + 3 * A;
    float* rstd1 = mean1 + ROWS;
    float* mean2 = rstd1 + ROWS;
    float* rstd2 = mean2 + ROWS;
    float* attn  = out;           // d_out as scratch until final FF2 write

    // 1. LN1 stats
    ln_stats_kernel<<<ROWS, 256, 0, stream>>>(x, mean1, rstd1);
    // 2. QKV GEMM (LN1 fused on A) with split-store -> q,k,v [B,H,N,D]
    gemm_kernel<<<dim3(3 * E_ / BN, ROWS / BM), 256, 0, stream>>>(
        x, qkv_w, qkv_b, nullptr, nullptr, qb, kb, vb,
        mean1, rstd1, ln1_g, ln1_b, ROWS, 3 * E_, E_, 0);
    // 3. attention -> attn (= d_out scratch), [b,n,(h d)] layout
    attn_kernel<<<dim3(N_, B_ * H_), 256, 0, stream>>>(qb, kb, vb, attn);
    // 4. proj GEMM + residual(x) -> x1
    gemm_kernel<<<dim3(E_ / BN, ROWS / BM), 256, 0, stream>>>(
        attn, proj_w, proj_b, x, x1, nullptr, nullptr, nullptr,
        nullptr, nullptr, nullptr, nullptr, ROWS, E_, E_, 0);
    // 5. LN2 stats
    ln_stats_kernel<<<ROWS, 256, 0, stream>>>(x1, mean2, rstd2);
    // 6. FF1 GEMM (LN2 fused on A) + exact GELU -> ffh
    gemm_kernel<<<dim3(HID_ / BN, ROWS / BM), 256, 0, stream>>>(
        x1, ff1_w, ff1_b, nullptr, ffh, nullptr, nullptr, nullptr,
        mean2, rstd2, ln2_g, ln2_b, ROWS, HID_, E_, 1);
    // 7. FF2 GEMM + residual(x1) -> out
    gemm_kernel<<<dim3(E_ / BN, ROWS / BM), 256, 0, stream>>>(
        ffh, ff2_w, ff2_b, x1, out, nullptr, nullptr, nullptr,
        nullptr, nullptr, nullptr, nullptr, ROWS, E_, HID_, 0);
}

// Round 3
// 2486.160 us; speedup vs baseline: 5.9629x; 5.9629x over previous
//
#include <hip/hip_runtime.h>
#include <cstddef>

// Problem constants (fixed by the reference).
#define B_   16
#define N_   1024
#define E_   768
#define H_   8
#define D_   96          // E_/H_
#define HID_ 1536        // 2*E_
#define ROWS (B_ * N_)   // 16384
#define SCALE_ 0.03608439182435161f  // 1/sqrt(768)

typedef __attribute__((ext_vector_type(8))) short bf16x8;
typedef __attribute__((ext_vector_type(4))) float f32x4;

__device__ __forceinline__ unsigned short f2bf(float f) {
    union { float f; unsigned int u; } c; c.f = f;
    unsigned int u = c.u + 0x7FFFu + ((c.u >> 16) & 1u);  // RNE
    return (unsigned short)(u >> 16);
}

// ---------------------------------------------------------------------------
// Per-row LayerNorm statistics: mean[row], rstd[row]. One block per row.
// ---------------------------------------------------------------------------
__global__ __launch_bounds__(256) void ln_stats_kernel(const float* __restrict__ x,
                                                       float* __restrict__ mean,
                                                       float* __restrict__ rstd) {
    int row = blockIdx.x;
    int tid = threadIdx.x;
    const float* xr = x + (size_t)row * E_;
    float v0 = xr[tid];
    float v1 = xr[tid + 256];
    float v2 = xr[tid + 512];
    float s  = v0 + v1 + v2;
    float s2 = v0 * v0 + v1 * v1 + v2 * v2;
#pragma unroll
    for (int off = 32; off > 0; off >>= 1) {
        s  += __shfl_down(s, off);
        s2 += __shfl_down(s2, off);
    }
    __shared__ float sb[8];
    int lane = tid & 63, wid = tid >> 6;
    if (lane == 0) { sb[wid] = s; sb[4 + wid] = s2; }
    __syncthreads();
    if (tid == 0) {
        float S  = sb[0] + sb[1] + sb[2] + sb[3];
        float S2 = sb[4] + sb[5] + sb[6] + sb[7];
        float m = S * (1.0f / E_);
        float v = S2 * (1.0f / E_) - m * m;
        mean[row] = m;
        rstd[row] = rsqrtf(v + 1e-5f);
    }
}

// ---------------------------------------------------------------------------
// FP32 tiled GEMM (unchanged core). Split-store epilogue now emits bf16
// q (x SCALE_), k, and TRANSPOSED v^T [b,h,d,n] for the MFMA attention.
// ---------------------------------------------------------------------------
#define BM 64
#define BN 64
#define BK 16

__device__ __forceinline__ float gelu_exact(float x) {
    return 0.5f * x * (1.0f + erff(x * 0.7071067811865475f));
}

__global__ __launch_bounds__(256) void gemm_kernel(
    const float* __restrict__ A, const float* __restrict__ W,
    const float* __restrict__ bias, const float* __restrict__ residual,
    float* __restrict__ C,
    unsigned short* __restrict__ qout, unsigned short* __restrict__ kout,
    unsigned short* __restrict__ vout,
    const float* __restrict__ ln_mean, const float* __restrict__ ln_rstd,
    const float* __restrict__ ln_g, const float* __restrict__ ln_beta,
    int M, int N, int K, int do_gelu)
{
    __shared__ float As[BK][BM + 1];
    __shared__ float Bs[BK][BN];
    int tid = threadIdx.x;
    int bm = blockIdx.y * BM;
    int bn = blockIdx.x * BN;
    int tx = tid & 15, ty = tid >> 4;
    int a_m = tid >> 2;
    int a_k = (tid & 3) << 2;
    int b_k = tid >> 4;
    int b_n = (tid & 15) << 2;
    const float* Aptr = A + (size_t)(bm + a_m) * K + a_k;
    const float* Wptr = W + (size_t)b_k * N + bn + b_n;

    float lmean = 0.f, lrstd = 1.f;
    if (ln_mean) { lmean = ln_mean[bm + a_m]; lrstd = ln_rstd[bm + a_m]; }

    float acc[4][4] = {};
    for (int k0 = 0; k0 < K; k0 += BK) {
        float4 av = *(const float4*)(Aptr + k0);
        if (ln_mean) {
            float4 gv = *(const float4*)(ln_g + k0 + a_k);
            float4 bv = *(const float4*)(ln_beta + k0 + a_k);
            av.x = (av.x - lmean) * lrstd * gv.x + bv.x;
            av.y = (av.y - lmean) * lrstd * gv.y + bv.y;
            av.z = (av.z - lmean) * lrstd * gv.z + bv.z;
            av.w = (av.w - lmean) * lrstd * gv.w + bv.w;
        }
        float4 wv = *(const float4*)(Wptr + (size_t)k0 * N);
        __syncthreads();
        As[a_k + 0][a_m] = av.x;
        As[a_k + 1][a_m] = av.y;
        As[a_k + 2][a_m] = av.z;
        As[a_k + 3][a_m] = av.w;
        *(float4*)&Bs[b_k][b_n] = wv;
        __syncthreads();
#pragma unroll
        for (int kk = 0; kk < BK; ++kk) {
            float a0 = As[kk][ty * 4 + 0];
            float a1 = As[kk][ty * 4 + 1];
            float a2 = As[kk][ty * 4 + 2];
            float a3 = As[kk][ty * 4 + 3];
            float b0 = Bs[kk][tx * 4 + 0];
            float b1 = Bs[kk][tx * 4 + 1];
            float b2 = Bs[kk][tx * 4 + 2];
            float b3 = Bs[kk][tx * 4 + 3];
            acc[0][0] += a0 * b0; acc[0][1] += a0 * b1; acc[0][2] += a0 * b2; acc[0][3] += a0 * b3;
            acc[1][0] += a1 * b0; acc[1][1] += a1 * b1; acc[1][2] += a1 * b2; acc[1][3] += a1 * b3;
            acc[2][0] += a2 * b0; acc[2][1] += a2 * b1; acc[2][2] += a2 * b2; acc[2][3] += a2 * b3;
            acc[3][0] += a3 * b0; acc[3][1] += a3 * b1; acc[3][2] += a3 * b2; acc[3][3] += a3 * b3;
        }
    }
#pragma unroll
    for (int i = 0; i < 4; ++i) {
        int m = bm + ty * 4 + i;
#pragma unroll
        for (int j = 0; j < 4; ++j) {
            int n = bn + tx * 4 + j;
            float c = acc[i][j] + bias[n];
            if (qout) {
                // de-interleave (h d t): n = (h*D + d)*3 + t
                int e = n / 3, t = n - e * 3;
                int hh = e / D_, dd = e - hh * D_;
                int b = m >> 10, ntok = m & (N_ - 1);
                size_t bh = (size_t)b * H_ + hh;
                if (t == 0)      qout[(bh * N_ + ntok) * D_ + dd] = f2bf(c * SCALE_);
                else if (t == 1) kout[(bh * N_ + ntok) * D_ + dd] = f2bf(c);
                else             vout[(bh * D_ + dd) * N_ + ntok] = f2bf(c);  // v^T
            } else {
                if (do_gelu) c = gelu_exact(c);
                if (residual) c += residual[(size_t)m * N + n];
                C[(size_t)m * N + n] = c;
            }
        }
    }
}

// ---------------------------------------------------------------------------
// Flash attention, bf16 MFMA (16x16x32), fp32 online softmax.
// Block = (bh, 64-row Q-tile), 4 waves x 16 q-rows. KV-tiles of 64.
// Swapped QK^T: S^T = K * Q^T so lane holds S^T[kv][q=lane&15] -> softmax is
// 16 reg ops + 2 shfl_xor. PV computes O^T = V^T * P^T.
// ---------------------------------------------------------------------------
#define QT  64
#define KVT 64
#define KST 104   // K/Q LDS row stride (bf16): 208 B = 13*16, 2-way bank alias
#define VST 88    // V^T LDS row stride (bf16): 176 B = 11*16

__global__ __launch_bounds__(256) void fattn_kernel(
    const unsigned short* __restrict__ qg, const unsigned short* __restrict__ kg,
    const unsigned short* __restrict__ vtg, float* __restrict__ out) {
    int bh = blockIdx.y;           // b*H + h
    int b = bh >> 3, h = bh & 7;
    int q0 = blockIdx.x * QT;
    int tid = threadIdx.x;
    int l = tid & 63, w = tid >> 6;
    int q16 = l & 15, g = l >> 4;
    int hi2 = (l >> 5) & 1;

    __shared__ __align__(16) unsigned short Qs[QT * KST];
    __shared__ __align__(16) unsigned short Ks[KVT * KST];
    __shared__ __align__(16) unsigned short Vts[D_ * VST];

    // ---- stage Q tile (once): 64 rows x 96 bf16, 48 B per thread ----
    {
        int row = tid >> 2, c8 = (tid & 3) * 24;   // ushort offsets
        const uint4* src = (const uint4*)(qg + ((size_t)bh * N_ + q0 + row) * D_ + c8);
        uint4* dst = (uint4*)(Qs + row * KST + c8);
#pragma unroll
        for (int i = 0; i < 3; ++i) dst[i] = src[i];
    }
    __syncthreads();

    // per-wave Q fragments (B-operand of swapped QK^T), held in regs
    bf16x8 qf[3];
#pragma unroll
    for (int dc = 0; dc < 3; ++dc)
        qf[dc] = *(const bf16x8*)&Qs[(w * 16 + q16) * KST + dc * 32 + g * 8];

    float m_run = -INFINITY, l_run = 0.f;
    f32x4 oacc[6] = {};

    for (int kt = 0; kt < N_ / KVT; ++kt) {
        __syncthreads();
        // ---- stage K tile: rows kt*64.. , same mapping as Q ----
        {
            int row = tid >> 2, c8 = (tid & 3) * 24;
            const uint4* src = (const uint4*)(kg + ((size_t)bh * N_ + kt * KVT + row) * D_ + c8);
            uint4* dst = (uint4*)(Ks + row * KST + c8);
#pragma unroll
            for (int i = 0; i < 3; ++i) dst[i] = src[i];
        }
        // ---- stage V^T tile: 96 d-rows x 64 kv bf16 ----
        {
            int c8 = (tid & 7) * 8;
#pragma unroll
            for (int p = 0; p < 3; ++p) {
                int row = (tid >> 3) + p * 32;
                *(uint4*)(Vts + row * VST + c8) =
                    *(const uint4*)(vtg + ((size_t)bh * D_ + row) * N_ + kt * KVT + c8);
            }
        }
        __syncthreads();

        // ---- QK^T (swapped): sacc[sub] = S^T[kv=sub*16..][q], K=96 over 3 chunks
        f32x4 sacc[4] = {};
#pragma unroll
        for (int sub = 0; sub < 4; ++sub)
#pragma unroll
            for (int dc = 0; dc < 3; ++dc) {
                bf16x8 af = *(const bf16x8*)&Ks[(sub * 16 + q16) * KST + dc * 32 + g * 8];
                sacc[sub] = __builtin_amdgcn_mfma_f32_16x16x32_bf16(af, qf[dc], sacc[sub], 0, 0, 0);
            }

        // ---- online softmax (scale already folded into q) ----
        float pmax = -INFINITY;
#pragma unroll
        for (int s = 0; s < 4; ++s)
#pragma unroll
            for (int r = 0; r < 4; ++r) pmax = fmaxf(pmax, sacc[s][r]);
        pmax = fmaxf(pmax, __shfl_xor(pmax, 16));
        pmax = fmaxf(pmax, __shfl_xor(pmax, 32));
        float m_new = fmaxf(m_run, pmax);
        float fac = __expf(m_run - m_new);
        float pe[4][4];
        float rs = 0.f;
#pragma unroll
        for (int s = 0; s < 4; ++s)
#pragma unroll
            for (int r = 0; r < 4; ++r) {
                pe[s][r] = __expf(sacc[s][r] - m_new);
                rs += pe[s][r];
            }
        rs += __shfl_xor(rs, 16);
        rs += __shfl_xor(rs, 32);
        l_run = l_run * fac + rs;
        m_run = m_new;
#pragma unroll
        for (int d = 0; d < 6; ++d)
#pragma unroll
            for (int r = 0; r < 4; ++r) oacc[d][r] *= fac;

        // ---- redistribute P^T into PV B-frag layout: lane needs kv=g*8+e ----
        bf16x8 pf[2];
#pragma unroll
        for (int c = 0; c < 2; ++c)
#pragma unroll
            for (int e = 0; e < 8; ++e) {
                int gsrc = (((l >> 4) & 1) * 8 + e) >> 2;
                int src = q16 + (gsrc << 4);
                float va = __shfl(pe[c * 2][e & 3], src);
                float vb = __shfl(pe[c * 2 + 1][e & 3], src);
                pf[c][e] = (short)f2bf(hi2 ? vb : va);
            }

        // ---- PV: O^T[dsub] += V^T(16d x 32kv) * P^T(32kv x 16q) ----
#pragma unroll
        for (int dsub = 0; dsub < 6; ++dsub)
#pragma unroll
            for (int c = 0; c < 2; ++c) {
                bf16x8 vf = *(const bf16x8*)&Vts[(dsub * 16 + q16) * VST + c * 32 + g * 8];
                oacc[dsub] = __builtin_amdgcn_mfma_f32_16x16x32_bf16(vf, pf[c], oacc[dsub], 0, 0, 0);
            }
    }

    // ---- epilogue: O[q][d] = oacc/l_run, written to [b,n,(h d)] fp32 ----
    float inv = 1.0f / l_run;
    int qrow = q0 + w * 16 + q16;
    size_t base = ((size_t)(b * N_ + qrow)) * E_ + h * D_;
#pragma unroll
    for (int dsub = 0; dsub < 6; ++dsub)
#pragma unroll
        for (int r = 0; r < 4; ++r)
            out[base + dsub * 16 + g * 4 + r] = oacc[dsub][r] * inv;
}

// ---------------------------------------------------------------------------
// Orchestration. Workspace (A = B*N*E = 12,582,912 floats) — 3A + 64KB total:
//   phase 1: q_bf16 [0, A/2)  k_bf16 [A/2, A)  vT_bf16 [A, 1.5A)
//   phase 2: x1 [0,A)  ffh [A,3A)          (q/k/vT dead after attention)
//   stats at [3A): mean1,rstd1,mean2,rstd2
//   d_out doubles as the attention-output scratch (fp32).
// ---------------------------------------------------------------------------
extern "C" void kernel_launch(void* const* d_in, const int* in_sizes, int n_in,
                              void* d_out, int out_size, void* d_ws, size_t ws_size,
                              hipStream_t stream) {
    const float* x      = (const float*)d_in[0];
    const float* ln1_g  = (const float*)d_in[1];
    const float* ln1_b  = (const float*)d_in[2];
    const float* qkv_w  = (const float*)d_in[3];
    const float* qkv_b  = (const float*)d_in[4];
    const float* proj_w = (const float*)d_in[5];
    const float* proj_b = (const float*)d_in[6];
    const float* ln2_g  = (const float*)d_in[7];
    const float* ln2_b  = (const float*)d_in[8];
    const float* ff1_w  = (const float*)d_in[9];
    const float* ff1_b  = (const float*)d_in[10];
    const float* ff2_w  = (const float*)d_in[11];
    const float* ff2_b  = (const float*)d_in[12];
    float* out = (float*)d_out;
    float* ws  = (float*)d_ws;

    const size_t A = (size_t)ROWS * E_;
    unsigned short* qb16 = (unsigned short*)ws;
    unsigned short* kb16 = (unsigned short*)(ws + A / 2);
    unsigned short* vt16 = (unsigned short*)(ws + A);
    float* x1    = ws;            // [0,A)   after attention
    float* ffh   = ws + A;        // [A,3A)  after attention
    float* mean1 = ws + 3 * A;
    float* rstd1 = mean1 + ROWS;
    float* mean2 = rstd1 + ROWS;
    float* rstd2 = mean2 + ROWS;
    float* attn  = out;           // d_out as scratch until final FF2 write

    // 1. LN1 stats
    ln_stats_kernel<<<ROWS, 256, 0, stream>>>(x, mean1, rstd1);
    // 2. QKV GEMM (LN1 fused) -> bf16 q (x SCALE), k, v^T
    gemm_kernel<<<dim3(3 * E_ / BN, ROWS / BM), 256, 0, stream>>>(
        x, qkv_w, qkv_b, nullptr, nullptr, qb16, kb16, vt16,
        mean1, rstd1, ln1_g, ln1_b, ROWS, 3 * E_, E_, 0);
    // 3. flash attention -> attn (= d_out scratch), [b,n,(h d)] fp32
    fattn_kernel<<<dim3(N_ / QT, B_ * H_), 256, 0, stream>>>(qb16, kb16, vt16, attn);
    // 4. proj GEMM + residual(x) -> x1
    gemm_kernel<<<dim3(E_ / BN, ROWS / BM), 256, 0, stream>>>(
        attn, proj_w, proj_b, x, x1, nullptr, nullptr, nullptr,
        nullptr, nullptr, nullptr, nullptr, ROWS, E_, E_, 0);
    // 5. LN2 stats
    ln_stats_kernel<<<ROWS, 256, 0, stream>>>(x1, mean2, rstd2);
    // 6. FF1 GEMM (LN2 fused) + exact GELU -> ffh
    gemm_kernel<<<dim3(HID_ / BN, ROWS / BM), 256, 0, stream>>>(
        x1, ff1_w, ff1_b, nullptr, ffh, nullptr, nullptr, nullptr,
        mean2, rstd2, ln2_g, ln2_b, ROWS, HID_, E_, 1);
    // 7. FF2 GEMM + residual(x1) -> out
    gemm_kernel<<<dim3(E_ / BN, ROWS / BM), 256, 0, stream>>>(
        ffh, ff2_w, ff2_b, x1, out, nullptr, nullptr, nullptr,
        nullptr, nullptr, nullptr, nullptr, ROWS, E_, HID_, 0);
}

// Round 4
// 657.011 us; speedup vs baseline: 22.5640x; 3.7840x over previous
//
#include <hip/hip_runtime.h>
#include <cstddef>

// Problem constants (fixed by the reference).
#define B_   16
#define N_   1024
#define E_   768
#define H_   8
#define D_   96          // E_/H_
#define HID_ 1536        // 2*E_
#define ROWS (B_ * N_)   // 16384
#define SCALE_ 0.03608439182435161f  // 1/sqrt(768)

typedef __attribute__((ext_vector_type(8))) short bf16x8;
typedef __attribute__((ext_vector_type(4))) float f32x4;

__device__ __forceinline__ unsigned short f2bf(float f) {
    union { float f; unsigned int u; } c; c.f = f;
    unsigned int u = c.u + 0x7FFFu + ((c.u >> 16) & 1u);  // RNE
    return (unsigned short)(u >> 16);
}

__device__ __forceinline__ void gload16(const void* g, void* l) {
    // async global->LDS, 16B per lane; LDS dest is wave-uniform base + lane*16
    __builtin_amdgcn_global_load_lds(
        (const __attribute__((address_space(1))) unsigned int*)g,
        (__attribute__((address_space(3))) unsigned int*)l, 16, 0, 0);
}

__device__ __forceinline__ float gelu_exact(float x) {
    return 0.5f * x * (1.0f + erff(x * 0.7071067811865475f));
}

// ---------------------------------------------------------------------------
// Weight convert+transpose: fp32 W[K][N] -> bf16 Wt[N][K]. 32x32 tiles.
// ---------------------------------------------------------------------------
__global__ __launch_bounds__(256) void wcvt_kernel(const float* __restrict__ W,
                                                   unsigned short* __restrict__ Wt,
                                                   int K, int N) {
    __shared__ float t[32][33];
    int n0 = blockIdx.x * 32, k0 = blockIdx.y * 32;
    int tr = threadIdx.x >> 3;          // 0..31
    int tc = (threadIdx.x & 7) * 4;     // 0,4,..,28
    float4 v = *(const float4*)&W[(size_t)(k0 + tr) * N + n0 + tc];
    t[tr][tc + 0] = v.x; t[tr][tc + 1] = v.y; t[tr][tc + 2] = v.z; t[tr][tc + 3] = v.w;
    __syncthreads();
    ushort4 o;
    o.x = f2bf(t[tc + 0][tr]);
    o.y = f2bf(t[tc + 1][tr]);
    o.z = f2bf(t[tc + 2][tr]);
    o.w = f2bf(t[tc + 3][tr]);
    *(ushort4*)&Wt[(size_t)(n0 + tr) * K + k0 + tc] = o;
}

// ---------------------------------------------------------------------------
// Fused LayerNorm -> bf16. One block per row of 768.
// ---------------------------------------------------------------------------
__global__ __launch_bounds__(256) void ln_fused_kernel(const float* __restrict__ x,
                                                       const float* __restrict__ g,
                                                       const float* __restrict__ beta,
                                                       unsigned short* __restrict__ out) {
    int row = blockIdx.x;
    int tid = threadIdx.x;
    const float* xr = x + (size_t)row * E_;
    float v0 = xr[tid];
    float v1 = xr[tid + 256];
    float v2 = xr[tid + 512];
    float s  = v0 + v1 + v2;
    float s2 = v0 * v0 + v1 * v1 + v2 * v2;
#pragma unroll
    for (int off = 32; off > 0; off >>= 1) {
        s  += __shfl_down(s, off);
        s2 += __shfl_down(s2, off);
    }
    __shared__ float sb[8];
    __shared__ float stats[2];
    int lane = tid & 63, wid = tid >> 6;
    if (lane == 0) { sb[wid] = s; sb[4 + wid] = s2; }
    __syncthreads();
    if (tid == 0) {
        float S  = sb[0] + sb[1] + sb[2] + sb[3];
        float S2 = sb[4] + sb[5] + sb[6] + sb[7];
        float m = S * (1.0f / E_);
        float var = S2 * (1.0f / E_) - m * m;
        stats[0] = m;
        stats[1] = rsqrtf(var + 1e-5f);
    }
    __syncthreads();
    float mean = stats[0], rstd = stats[1];
    unsigned short* orow = out + (size_t)row * E_;
    orow[tid]       = f2bf((v0 - mean) * rstd * g[tid]       + beta[tid]);
    orow[tid + 256] = f2bf((v1 - mean) * rstd * g[tid + 256] + beta[tid + 256]);
    orow[tid + 512] = f2bf((v2 - mean) * rstd * g[tid + 512] + beta[tid + 512]);
}

// ---------------------------------------------------------------------------
// bf16 MFMA GEMM (m97 structure): C = A[M][K] @ Wt[N][K]^T + bias, epilogues.
// 128x128 tile, BK=32, 4 waves (64x64 each), global_load_lds 16B staging,
// 2 barriers per K-step, 16 MFMA + 8 ds_read_b128 per K-step.
// MODE 0: C fp32 = acc + bias + R   (R may alias C: per-element RAW is safe)
// MODE 1: Cb bf16 = gelu(acc + bias)
// MODE 2: split-store q(*SCALE)/k bf16 [B,H,N,D], v^T bf16 [B,H,D,N]
// ---------------------------------------------------------------------------
template<int MODE>
__global__ __launch_bounds__(256) void bgemm_kernel(
    const unsigned short* __restrict__ A, const unsigned short* __restrict__ Wt,
    const float* __restrict__ bias,
    const float* R, float* C, unsigned short* Cb,
    unsigned short* qo, unsigned short* ko, unsigned short* vo,
    int M, int N, int K)
{
    __shared__ __align__(16) unsigned short As[128 * 32];
    __shared__ __align__(16) unsigned short Bs[128 * 32];
    const int tid = threadIdx.x;
    const int l = tid & 63, w = tid >> 6;
    const int bm = blockIdx.y * 128, bn = blockIdx.x * 128;
    const int wr = (w >> 1) * 64, wc = (w & 1) * 64;
    const int l15 = l & 15, l4 = l >> 4;

    // staging mapping: wave w, inst i in {0,1}: rows w*16 + i*64 + (l>>2),
    // k-cols (l&3)*8 .. +8  (1 KB per wave-inst, LDS linear)
    const int srow = w * 16 + (l >> 2);
    const int scol = (l & 3) * 8;
    const unsigned short* Ag = A  + (size_t)(bm + srow) * K + scol;
    const unsigned short* Wg = Wt + (size_t)(bn + srow) * K + scol;
    unsigned short* AsW = As + w * 512;   // w*1024 bytes
    unsigned short* BsW = Bs + w * 512;

    f32x4 acc[4][4] = {};

    for (int k0 = 0; k0 < K; k0 += 32) {
        __syncthreads();   // previous compute done before overwrite
        gload16(Ag + k0,                  AsW);
        gload16(Ag + (size_t)64 * K + k0, AsW + 2048);
        gload16(Wg + k0,                  BsW);
        gload16(Wg + (size_t)64 * K + k0, BsW + 2048);
        __syncthreads();   // drains vmcnt: tiles ready
        bf16x8 af[4], bfr[4];
#pragma unroll
        for (int mi = 0; mi < 4; ++mi)
            af[mi] = *(const bf16x8*)&As[(wr + mi * 16 + l15) * 32 + l4 * 8];
#pragma unroll
        for (int ni = 0; ni < 4; ++ni)
            bfr[ni] = *(const bf16x8*)&Bs[(wc + ni * 16 + l15) * 32 + l4 * 8];
#pragma unroll
        for (int mi = 0; mi < 4; ++mi)
#pragma unroll
            for (int ni = 0; ni < 4; ++ni)
                acc[mi][ni] = __builtin_amdgcn_mfma_f32_16x16x32_bf16(
                    af[mi], bfr[ni], acc[mi][ni], 0, 0, 0);
    }

    // epilogue: C row = bm+wr+mi*16+(l>>4)*4+r, col = bn+wc+ni*16+(l&15)
    const int r0 = bm + wr + l4 * 4;
    const int c0 = bn + wc + l15;
    float bv[4];
#pragma unroll
    for (int ni = 0; ni < 4; ++ni) bv[ni] = bias[c0 + ni * 16];

#pragma unroll
    for (int mi = 0; mi < 4; ++mi) {
#pragma unroll
        for (int r = 0; r < 4; ++r) {
            int row = r0 + mi * 16 + r;
            if constexpr (MODE == 0) {
                size_t base = (size_t)row * N;
#pragma unroll
                for (int ni = 0; ni < 4; ++ni) {
                    size_t idx = base + c0 + ni * 16;
                    C[idx] = acc[mi][ni][r] + bv[ni] + R[idx];
                }
            } else if constexpr (MODE == 1) {
                size_t base = (size_t)row * N;
#pragma unroll
                for (int ni = 0; ni < 4; ++ni) {
                    size_t idx = base + c0 + ni * 16;
                    Cb[idx] = f2bf(gelu_exact(acc[mi][ni][r] + bv[ni]));
                }
            } else {
                int b = row >> 10, ntok = row & (N_ - 1);
#pragma unroll
                for (int ni = 0; ni < 4; ++ni) {
                    int n = c0 + ni * 16;
                    int e = n / 3, t = n - e * 3;
                    int hh = e / D_, dd = e - hh * D_;
                    float cval = acc[mi][ni][r] + bv[ni];
                    size_t bh = (size_t)(b * H_ + hh);
                    if (t == 0)      qo[(bh * N_ + ntok) * D_ + dd] = f2bf(cval * SCALE_);
                    else if (t == 1) ko[(bh * N_ + ntok) * D_ + dd] = f2bf(cval);
                    else             vo[(bh * D_ + dd) * N_ + ntok] = f2bf(cval);
                }
            }
        }
    }
}

// ---------------------------------------------------------------------------
// Flash attention, bf16 MFMA (16x16x32), fp32 online softmax. Output bf16.
// ---------------------------------------------------------------------------
#define QT  64
#define KVT 64
#define KST 104   // K/Q LDS row stride (bf16)
#define VST 88    // V^T LDS row stride (bf16)

__global__ __launch_bounds__(256) void fattn_kernel(
    const unsigned short* __restrict__ qg, const unsigned short* __restrict__ kg,
    const unsigned short* __restrict__ vtg, unsigned short* __restrict__ out) {
    int bh = blockIdx.y;
    int b = bh >> 3, h = bh & 7;
    int q0 = blockIdx.x * QT;
    int tid = threadIdx.x;
    int l = tid & 63, w = tid >> 6;
    int q16 = l & 15, g = l >> 4;
    int hi2 = (l >> 5) & 1;

    __shared__ __align__(16) unsigned short Qs[QT * KST];
    __shared__ __align__(16) unsigned short Ks[KVT * KST];
    __shared__ __align__(16) unsigned short Vts[D_ * VST];

    {
        int row = tid >> 2, c8 = (tid & 3) * 24;
        const uint4* src = (const uint4*)(qg + ((size_t)bh * N_ + q0 + row) * D_ + c8);
        uint4* dst = (uint4*)(Qs + row * KST + c8);
#pragma unroll
        for (int i = 0; i < 3; ++i) dst[i] = src[i];
    }
    __syncthreads();

    bf16x8 qf[3];
#pragma unroll
    for (int dc = 0; dc < 3; ++dc)
        qf[dc] = *(const bf16x8*)&Qs[(w * 16 + q16) * KST + dc * 32 + g * 8];

    float m_run = -INFINITY, l_run = 0.f;
    f32x4 oacc[6] = {};

    for (int kt = 0; kt < N_ / KVT; ++kt) {
        __syncthreads();
        {
            int row = tid >> 2, c8 = (tid & 3) * 24;
            const uint4* src = (const uint4*)(kg + ((size_t)bh * N_ + kt * KVT + row) * D_ + c8);
            uint4* dst = (uint4*)(Ks + row * KST + c8);
#pragma unroll
            for (int i = 0; i < 3; ++i) dst[i] = src[i];
        }
        {
            int c8 = (tid & 7) * 8;
#pragma unroll
            for (int p = 0; p < 3; ++p) {
                int row = (tid >> 3) + p * 32;
                *(uint4*)(Vts + row * VST + c8) =
                    *(const uint4*)(vtg + ((size_t)bh * D_ + row) * N_ + kt * KVT + c8);
            }
        }
        __syncthreads();

        f32x4 sacc[4] = {};
#pragma unroll
        for (int sub = 0; sub < 4; ++sub)
#pragma unroll
            for (int dc = 0; dc < 3; ++dc) {
                bf16x8 af = *(const bf16x8*)&Ks[(sub * 16 + q16) * KST + dc * 32 + g * 8];
                sacc[sub] = __builtin_amdgcn_mfma_f32_16x16x32_bf16(af, qf[dc], sacc[sub], 0, 0, 0);
            }

        float pmax = -INFINITY;
#pragma unroll
        for (int s = 0; s < 4; ++s)
#pragma unroll
            for (int r = 0; r < 4; ++r) pmax = fmaxf(pmax, sacc[s][r]);
        pmax = fmaxf(pmax, __shfl_xor(pmax, 16));
        pmax = fmaxf(pmax, __shfl_xor(pmax, 32));
        float m_new = fmaxf(m_run, pmax);
        float fac = __expf(m_run - m_new);
        float pe[4][4];
        float rs = 0.f;
#pragma unroll
        for (int s = 0; s < 4; ++s)
#pragma unroll
            for (int r = 0; r < 4; ++r) {
                pe[s][r] = __expf(sacc[s][r] - m_new);
                rs += pe[s][r];
            }
        rs += __shfl_xor(rs, 16);
        rs += __shfl_xor(rs, 32);
        l_run = l_run * fac + rs;
        m_run = m_new;
#pragma unroll
        for (int d = 0; d < 6; ++d)
#pragma unroll
            for (int r = 0; r < 4; ++r) oacc[d][r] *= fac;

        bf16x8 pf[2];
#pragma unroll
        for (int c = 0; c < 2; ++c)
#pragma unroll
            for (int e = 0; e < 8; ++e) {
                int gsrc = (((l >> 4) & 1) * 8 + e) >> 2;
                int src = q16 + (gsrc << 4);
                float va = __shfl(pe[c * 2][e & 3], src);
                float vb = __shfl(pe[c * 2 + 1][e & 3], src);
                pf[c][e] = (short)f2bf(hi2 ? vb : va);
            }

#pragma unroll
        for (int dsub = 0; dsub < 6; ++dsub)
#pragma unroll
            for (int c = 0; c < 2; ++c) {
                bf16x8 vf = *(const bf16x8*)&Vts[(dsub * 16 + q16) * VST + c * 32 + g * 8];
                oacc[dsub] = __builtin_amdgcn_mfma_f32_16x16x32_bf16(vf, pf[c], oacc[dsub], 0, 0, 0);
            }
    }

    float inv = 1.0f / l_run;
    int qrow = q0 + w * 16 + q16;
    size_t base = ((size_t)(b * N_ + qrow)) * E_ + h * D_;
#pragma unroll
    for (int dsub = 0; dsub < 6; ++dsub)
#pragma unroll
        for (int r = 0; r < 4; ++r)
            out[base + dsub * 16 + g * 4 + r] = f2bf(oacc[dsub][r] * inv);
}

// ---------------------------------------------------------------------------
// Orchestration. Workspace layout (floats; S = 6,291,456 = bf16 activation slot):
//   [0, 2359296)              bf16 weights: qkv_wt, proj_wt, ff1_wt, ff2_wt
//   R = 2359296:
//     R+0S..1S   h16 (LN1 out)   -> reused as attnb (fattn out)
//     R+1S..2S   q16             -> reused as h16b (LN2 out)
//     R+2S..3S   k16  \
//     R+3S..4S   vt16 / -> reused as ffh (FF1 out, 2 slots)
//   x1 lives IN d_out (proj writes it; FF2 reads residual in-place).
// Total ws = 27,525,120 floats = 110.1 MB.
// ---------------------------------------------------------------------------
extern "C" void kernel_launch(void* const* d_in, const int* in_sizes, int n_in,
                              void* d_out, int out_size, void* d_ws, size_t ws_size,
                              hipStream_t stream) {
    const float* x      = (const float*)d_in[0];
    const float* ln1_g  = (const float*)d_in[1];
    const float* ln1_b  = (const float*)d_in[2];
    const float* qkv_w  = (const float*)d_in[3];
    const float* qkv_b  = (const float*)d_in[4];
    const float* proj_w = (const float*)d_in[5];
    const float* proj_b = (const float*)d_in[6];
    const float* ln2_g  = (const float*)d_in[7];
    const float* ln2_b  = (const float*)d_in[8];
    const float* ff1_w  = (const float*)d_in[9];
    const float* ff1_b  = (const float*)d_in[10];
    const float* ff2_w  = (const float*)d_in[11];
    const float* ff2_b  = (const float*)d_in[12];
    float* out = (float*)d_out;
    float* ws  = (float*)d_ws;

    const size_t S = (size_t)ROWS * E_ / 2;       // 6,291,456 floats per bf16 slot
    unsigned short* qkv_wt = (unsigned short*)ws;                    // 2304x768
    unsigned short* proj_wt = qkv_wt + (size_t)3 * E_ * E_;          // 768x768
    unsigned short* ff1_wt  = proj_wt + (size_t)E_ * E_;             // 1536x768
    unsigned short* ff2_wt  = ff1_wt + (size_t)HID_ * E_;            // 768x1536
    float* Rb = ws + 2359296;
    unsigned short* h16   = (unsigned short*)(Rb);
    unsigned short* q16   = (unsigned short*)(Rb + S);
    unsigned short* k16   = (unsigned short*)(Rb + 2 * S);
    unsigned short* vt16  = (unsigned short*)(Rb + 3 * S);
    unsigned short* attnb = h16;                  // h16 dead after QKV GEMM
    unsigned short* h16b  = q16;                  // q dead after attention
    unsigned short* ffh   = k16;                  // k,v dead after attention (2 slots)
    float* x1 = out;                              // d_out as x1; FF2 reads in-place

    // 0. weights -> bf16 transposed [N][K]
    wcvt_kernel<<<dim3(3 * E_ / 32, E_ / 32), 256, 0, stream>>>(qkv_w, qkv_wt, E_, 3 * E_);
    wcvt_kernel<<<dim3(E_ / 32, E_ / 32), 256, 0, stream>>>(proj_w, proj_wt, E_, E_);
    wcvt_kernel<<<dim3(HID_ / 32, E_ / 32), 256, 0, stream>>>(ff1_w, ff1_wt, E_, HID_);
    wcvt_kernel<<<dim3(E_ / 32, HID_ / 32), 256, 0, stream>>>(ff2_w, ff2_wt, HID_, E_);
    // 1. LN1 -> bf16
    ln_fused_kernel<<<ROWS, 256, 0, stream>>>(x, ln1_g, ln1_b, h16);
    // 2. QKV GEMM -> q(xSCALE), k, v^T bf16
    bgemm_kernel<2><<<dim3(3 * E_ / 128, ROWS / 128), 256, 0, stream>>>(
        h16, qkv_wt, qkv_b, nullptr, nullptr, nullptr, q16, k16, vt16,
        ROWS, 3 * E_, E_);
    // 3. flash attention -> attnb bf16 [b,n,(h d)]
    fattn_kernel<<<dim3(N_ / QT, B_ * H_), 256, 0, stream>>>(q16, k16, vt16, attnb);
    // 4. proj GEMM + residual(x) -> x1 (= d_out) fp32
    bgemm_kernel<0><<<dim3(E_ / 128, ROWS / 128), 256, 0, stream>>>(
        attnb, proj_wt, proj_b, x, x1, nullptr, nullptr, nullptr, nullptr,
        ROWS, E_, E_);
    // 5. LN2 -> bf16
    ln_fused_kernel<<<ROWS, 256, 0, stream>>>(x1, ln2_g, ln2_b, h16b);
    // 6. FF1 GEMM + GELU -> ffh bf16
    bgemm_kernel<1><<<dim3(HID_ / 128, ROWS / 128), 256, 0, stream>>>(
        h16b, ff1_wt, ff1_b, nullptr, nullptr, ffh, nullptr, nullptr, nullptr,
        ROWS, HID_, E_);
    // 7. FF2 GEMM + residual(x1, in-place) -> out fp32
    bgemm_kernel<0><<<dim3(E_ / 128, ROWS / 128), 256, 0, stream>>>(
        ffh, ff2_wt, ff2_b, x1, out, nullptr, nullptr, nullptr, nullptr,
        ROWS, E_, HID_);
}